// Round 3
// baseline (345.630 us; speedup 1.0000x reference)
//
#include <hip/hip_runtime.h>
#include <hip/hip_bf16.h>

#define D_DIM 128
#define TILE 128
#define LDS_K (D_DIM + 8)   // +16B row pad -> 4-bank rotation; b128 access = 2-way, free (m136)

typedef __attribute__((ext_vector_type(8))) short short8;   // 8 bf16 = MFMA A/B frag (4 VGPRs)
typedef __attribute__((ext_vector_type(4))) float floatx4;  // MFMA C/D frag

// ---------------------------------------------------------------------------
// Single fused kernel — NO workspace, reads only d_in. Each block:
//   1. stages its 128x128 f32 A/B tiles, rounding to bf16 into LDS,
//      computing row sum-of-squares of the ROUNDED values (so
//      d2 = ||a_hat-b_hat||^2 >= 0 exactly) via 16-lane shuffle reduce.
//   2. 4 waves in 2x2, each wave a 64x64 subtile = 4x4 grid of
//      16x16x32 bf16 MFMAs, K=128 in one LDS stage.
//   3. fused epilogue -sqrt(max(a2+b2-2ab,0)) with float4 stores.
//
// OPERAND SWAP (verified R2, initial check absmax 0.125): A-operand := m-tile
// rows, B-operand := n-tile rows. C/D layout (m89/m91: row=(lane>>4)*4+reg,
// col=lane&15) then gives
//   m = mBase + i*16 + (lane>>4)*4 + reg   (4 consecutive output columns)
//   n = nBase + j*16 + (lane&15)
// so each floatx4 acc is one global_store_dwordx4 at out[n*M + m].
// ---------------------------------------------------------------------------
__global__ __launch_bounds__(256, 2)
void dist_kernel(const float* __restrict__ za, const float* __restrict__ zb,
                 float* __restrict__ out, int M) {
    __shared__ __hip_bfloat16 As[TILE][LDS_K];   // z_anc tile (n rows)
    __shared__ __hip_bfloat16 Bs[TILE][LDS_K];   // z_pos_neg tile (m rows)
    __shared__ alignas(16) float a2s[TILE];
    __shared__ alignas(16) float b2s[TILE];

    const int nBase = blockIdx.y * TILE;   // output row block
    const int mBase = blockIdx.x * TILE;   // output col block
    const int tid = threadIdx.x;
    const int lane = tid & 63;

    // ---- stage + convert + row norms: passes 0..7 -> A tile, 8..15 -> B ----
    // idx = (pass&7)*256 + tid: row = idx>>4 (lanes 0-15 share a row),
    // kc = (idx&15)*8 -> each thread loads 8 f32 (2x float4, coalesced
    // 512B per 16 lanes), rounds to bf16, writes one 16B LDS chunk.
    #pragma unroll
    for (int pass = 0; pass < 16; ++pass) {
        const bool isA = pass < 8;
        const int idx = (pass & 7) * 256 + tid;     // 0..2047
        const int row = idx >> 4;                   // 0..127
        const int kc = (idx & 15) * 8;
        const float* src = isA ? (za + ((size_t)(nBase + row) * D_DIM + kc))
                               : (zb + ((size_t)(mBase + row) * D_DIM + kc));
        const float4 v0 = ((const float4*)src)[0];
        const float4 v1 = ((const float4*)src)[1];
        __hip_bfloat16 h[8];
        h[0] = __float2bfloat16(v0.x); h[1] = __float2bfloat16(v0.y);
        h[2] = __float2bfloat16(v0.z); h[3] = __float2bfloat16(v0.w);
        h[4] = __float2bfloat16(v1.x); h[5] = __float2bfloat16(v1.y);
        h[6] = __float2bfloat16(v1.z); h[7] = __float2bfloat16(v1.w);
        short8 pk;
        float ss = 0.0f;
        #pragma unroll
        for (int t = 0; t < 8; ++t) {
            pk[t] = (short)__builtin_bit_cast(unsigned short, h[t]);
            const float f = __bfloat162float(h[t]);
            ss = fmaf(f, f, ss);
        }
        *(short8*)(isA ? &As[row][kc] : &Bs[row][kc]) = pk;
        // reduce ss across the 16 lanes sharing this row
        #pragma unroll
        for (int off = 1; off < 16; off <<= 1) ss += __shfl_xor(ss, off, 64);
        if ((lane & 15) == 0) (isA ? a2s : b2s)[row] = ss;
    }
    __syncthreads();

    // ---- MFMA: 4x4 grid of 16x16x32 per wave, K=128 in 4 steps ----
    const int wave = tid >> 6;
    const int wm = (wave & 1) * 64;          // wave offset in m
    const int wn = (wave >> 1) * 64;         // wave offset in n
    const int lrow = lane & 15;
    const int lk = (lane >> 4) * 8;

    floatx4 acc[4][4] = {};                  // [i: m-frag][j: n-frag]
    #pragma unroll
    for (int ks = 0; ks < 4; ++ks) {
        const int k0 = ks * 32 + lk;
        short8 mfr[4], nfr[4];
        #pragma unroll
        for (int i = 0; i < 4; ++i)
            mfr[i] = *(const short8*)(&Bs[wm + i * 16 + lrow][k0]);   // m-dim -> A operand
        #pragma unroll
        for (int j = 0; j < 4; ++j)
            nfr[j] = *(const short8*)(&As[wn + j * 16 + lrow][k0]);   // n-dim -> B operand
        #pragma unroll
        for (int i = 0; i < 4; ++i)
            #pragma unroll
            for (int j = 0; j < 4; ++j)
                acc[i][j] = __builtin_amdgcn_mfma_f32_16x16x32_bf16(mfr[i], nfr[j], acc[i][j], 0, 0, 0);
    }

    // ---- epilogue: out[n][m] = -sqrt(max(a2[n]+b2[m]-2ab, 0)), float4 ----
    const int mLoc = wm + (lane >> 4) * 4;   // 4 consecutive m per acc frag
    const int nLoc0 = wn + lrow;

    float4 b2v[4];
    #pragma unroll
    for (int i = 0; i < 4; ++i)
        b2v[i] = *(const float4*)(&b2s[mLoc + i * 16]);

    #pragma unroll
    for (int j = 0; j < 4; ++j) {
        const int n = nBase + nLoc0 + j * 16;
        const float an = a2s[nLoc0 + j * 16];
        float* orow = out + (size_t)n * (size_t)M + mBase;
        #pragma unroll
        for (int i = 0; i < 4; ++i) {
            float4 v;
            const float d2x = fmaxf(fmaf(-2.0f, acc[i][j][0], an + b2v[i].x), 0.0f);
            const float d2y = fmaxf(fmaf(-2.0f, acc[i][j][1], an + b2v[i].y), 0.0f);
            const float d2z = fmaxf(fmaf(-2.0f, acc[i][j][2], an + b2v[i].z), 0.0f);
            const float d2w = fmaxf(fmaf(-2.0f, acc[i][j][3], an + b2v[i].w), 0.0f);
            v.x = -__builtin_amdgcn_sqrtf(d2x);
            v.y = -__builtin_amdgcn_sqrtf(d2y);
            v.z = -__builtin_amdgcn_sqrtf(d2z);
            v.w = -__builtin_amdgcn_sqrtf(d2w);
            *(float4*)(orow + mLoc + i * 16) = v;
        }
    }
}

extern "C" void kernel_launch(void* const* d_in, const int* in_sizes, int n_in,
                              void* d_out, int out_size, void* d_ws, size_t ws_size,
                              hipStream_t stream) {
    const float* za = (const float*)d_in[0];
    const float* zb = (const float*)d_in[1];
    const int N = in_sizes[0] / D_DIM;   // 8192
    const int M = in_sizes[1] / D_DIM;   // 8192
    float* out = (float*)d_out;

    dim3 grid(M / TILE, N / TILE);
    dist_kernel<<<grid, 256, 0, stream>>>(za, zb, out, M);
}